// Round 1
// baseline (339.930 us; speedup 1.0000x reference)
//
#include <hip/hip_runtime.h>
#include <hip/hip_bf16.h>
#include <stdint.h>

#define BDIM 4
#define CDIM 512
#define HDIM 128
#define WDIM 128
#define HWDIM (HDIM*WDIM)
#define SADMP 16
#define BHW 8          // window height/width (bh=bw=8)
#define KKP 256        // keypoints = 16*16

// ---------------- K1: resp[b][hw] = sum_c A[b][c][hw] ----------------
__global__ void resp_kernel(const float* __restrict__ A, float* __restrict__ resp) {
    int gid = blockIdx.x * blockDim.x + threadIdx.x;   // 0 .. B*HW-1
    int b = gid / HWDIM, hw = gid % HWDIM;
    const float* p = A + (size_t)b * CDIM * HWDIM + hw;
    float s0 = 0.f, s1 = 0.f, s2 = 0.f, s3 = 0.f;
    #pragma unroll 4
    for (int c = 0; c < CDIM; c += 4) {
        s0 += p[(size_t)(c + 0) * HWDIM];
        s1 += p[(size_t)(c + 1) * HWDIM];
        s2 += p[(size_t)(c + 2) * HWDIM];
        s3 += p[(size_t)(c + 3) * HWDIM];
    }
    resp[gid] = (s0 + s1) + (s2 + s3);
}

// ---------------- K2: per-window argmax (first occurrence) ----------------
__global__ void argmax_kernel(const float* __restrict__ resp, int* __restrict__ kp) {
    int win = blockIdx.x;                 // b*K + k
    int b = win / KKP, k = win % KKP;
    int bi = k / SADMP, bj = k % SADMP;
    int l = threadIdx.x;                  // 0..63 == loc (row-major r*8+c)
    int r = l >> 3, c = l & 7;
    int h = bi * BHW + r, w = bj * BHW + c;
    float v = resp[b * HWDIM + h * WDIM + w];
    int idx = l;
    #pragma unroll
    for (int off = 32; off; off >>= 1) {
        float ov = __shfl_down(v, off);
        int   oi = __shfl_down(idx, off);
        if (ov > v || (ov == v && oi < idx)) { v = ov; idx = oi; }
    }
    if (l == 0) {
        int row = bi * BHW + (idx >> 3);
        int col = bj * BHW + (idx & 7);
        kp[win] = row * WDIM + col;       // flat index into H*W
    }
}

// ---------------- K3: gather desc[b][c][k] = A[b][c][kp[b][k]] ----------------
__global__ void gather_kernel(const float* __restrict__ A, const int* __restrict__ kp,
                              float* __restrict__ desc) {
    int bc = blockIdx.x;                  // b*C + c
    int b  = bc / CDIM;
    int k  = threadIdx.x;                 // 0..255
    int idx = kp[b * KKP + k];
    desc[(size_t)bc * KKP + k] = A[(size_t)bc * HWDIM + idx];
}

// ---------------- K4: dn[b][k] = sum_c desc^2 ----------------
__global__ void dn_kernel(const float* __restrict__ desc, float* __restrict__ dn) {
    int b = blockIdx.x;
    int k = threadIdx.x;
    const float* p = desc + (size_t)b * CDIM * KKP + k;
    float s = 0.f;
    #pragma unroll 8
    for (int c = 0; c < CDIM; c++) {
        float v = p[(size_t)c * KKP];
        s = fmaf(v, v, s);
    }
    dn[b * KKP + k] = s;
}

// ---------------- K5: cross GEMM + dist + per-k argmin via atomicMin ----------------
__device__ __forceinline__ unsigned int ordf(float f) {
    unsigned u = __float_as_uint(f);
    return (u & 0x80000000u) ? ~u : (u | 0x80000000u);
}

__global__ __launch_bounds__(256) void dist_kernel(
    const float* __restrict__ desc, const float* __restrict__ fb,
    const float* __restrict__ dn, unsigned long long* __restrict__ minkey)
{
    int kt = blockIdx.x;                  // 0..3   (k-tile of 64)
    int nt = blockIdx.y;                  // 0..255 (n-tile of 64)
    int b  = blockIdx.z;
    int k0 = kt * 64, n0 = nt * 64;
    int t  = threadIdx.x;
    int ty = t >> 4, tx = t & 15;         // 16x16 thread grid, 4x4 outputs each

    __shared__ float sA[64][64];          // desc tile  [c][k]
    __shared__ float sB[64][64];          // fb tile    [c][n]
    __shared__ float bnp[4][64];
    __shared__ float bnf[64];

    float acc[4][4] = {};
    float bnacc = 0.f;
    const int col = t & 63, rbase = t >> 6;

    for (int cc = 0; cc < CDIM; cc += 64) {
        #pragma unroll
        for (int i = 0; i < 16; i++) {
            int r = i * 4 + rbase;
            sA[r][col] = desc[((size_t)(b * CDIM + cc + r)) * KKP + k0 + col];
            float v    = fb  [((size_t)(b * CDIM + cc + r)) * HWDIM + n0 + col];
            sB[r][col] = v;
            bnacc = fmaf(v, v, bnacc);    // fused bn for this column
        }
        __syncthreads();
        #pragma unroll 8
        for (int c = 0; c < 64; c++) {
            const float4 a4 = *reinterpret_cast<const float4*>(&sA[c][ty * 4]);
            const float4 b4 = *reinterpret_cast<const float4*>(&sB[c][tx * 4]);
            const float av[4] = {a4.x, a4.y, a4.z, a4.w};
            const float bv[4] = {b4.x, b4.y, b4.z, b4.w};
            #pragma unroll
            for (int i = 0; i < 4; i++)
                #pragma unroll
                for (int j = 0; j < 4; j++)
                    acc[i][j] = fmaf(av[i], bv[j], acc[i][j]);
        }
        __syncthreads();
    }
    bnp[rbase][col] = bnacc;
    __syncthreads();
    if (t < 64) bnf[t] = (bnp[0][t] + bnp[1][t]) + (bnp[2][t] + bnp[3][t]);
    __syncthreads();

    #pragma unroll
    for (int i = 0; i < 4; i++) {
        int k = k0 + ty * 4 + i;
        float dnk = dn[b * KKP + k];
        unsigned long long best = ~0ull;
        #pragma unroll
        for (int j = 0; j < 4; j++) {
            int n = n0 + tx * 4 + j;
            float d = dnk - 2.f * acc[i][j] + bnf[tx * 4 + j];
            unsigned long long key = ((unsigned long long)ordf(d) << 32) | (unsigned)n;
            if (key < best) best = key;   // min dist, tie -> min n
        }
        #pragma unroll
        for (int off = 8; off; off >>= 1) {
            unsigned long long o = __shfl_xor(best, off);
            if (o < best) best = o;
        }
        if (tx == 0) atomicMin(&minkey[b * KKP + k], best);
    }
}

// ---------------- K6: finalize — decode min, per-batch mode, write outputs ----------------
__global__ void finalize_kernel(const unsigned long long* __restrict__ minkey,
                                const int* __restrict__ kp,
                                float* __restrict__ out)
{
    int b = blockIdx.x;
    int k = threadIdx.x;                  // 0..255
    unsigned long long key = minkey[b * KKP + k];
    unsigned n   = (unsigned)(key & 0xffffffffu);
    unsigned top = (unsigned)(key >> 32);
    unsigned fbits = (top & 0x80000000u) ? (top ^ 0x80000000u) : ~top;
    out[8 + b * KKP + k] = __uint_as_float(fbits);   // min_vals

    int idxA = kp[b * KKP + k];
    int rowA = idxA >> 7, colA = idxA & 127;
    int rowB = (int)(n >> 7), colB = (int)(n & 127);
    int drow = rowA - rowB, dcol = colA - colB;
    int code = (drow + 256) * 1024 + (dcol + 256);   // unique, positive

    __shared__ int codes[KKP];
    __shared__ int keys[KKP];
    codes[k] = code;
    __syncthreads();
    int cnt = 0;
    for (int j = 0; j < KKP; j++) cnt += (codes[j] == code);
    keys[k] = cnt * 256 + (255 - k);      // max count, tie -> smallest k
    __syncthreads();
    for (int s = 128; s; s >>= 1) {
        if (k < s) keys[k] = max(keys[k], keys[k + s]);
        __syncthreads();
    }
    if (k == 0) {
        int bestk = 255 - (keys[0] & 255);
        int bc = codes[bestk];
        int dr = bc / 1024 - 256, dc = bc % 1024 - 256;
        out[b * 2 + 0] = (float)dr;       // dx = drow
        out[b * 2 + 1] = (float)dc;       // dy = dcol
    }
}

extern "C" void kernel_launch(void* const* d_in, const int* in_sizes, int n_in,
                              void* d_out, int out_size, void* d_ws, size_t ws_size,
                              hipStream_t stream) {
    const float* A  = (const float*)d_in[0];
    const float* Bf = (const float*)d_in[1];
    float* out = (float*)d_out;
    char* ws = (char*)d_ws;

    float* resp = (float*)ws;                                   // 256 KB
    int*   kp   = (int*)(ws + 262144);                          // 4 KB
    float* dn   = (float*)(ws + 262144 + 4096);                 // 4 KB
    unsigned long long* minkey = (unsigned long long*)(ws + 262144 + 8192); // 8 KB
    float* desc = (float*)(ws + 262144 + 8192 + 8192);          // 2 MB

    hipMemsetAsync(minkey, 0xFF, BDIM * KKP * sizeof(unsigned long long), stream);
    resp_kernel<<<BDIM * HWDIM / 256, 256, 0, stream>>>(A, resp);
    argmax_kernel<<<BDIM * KKP, 64, 0, stream>>>(resp, kp);
    gather_kernel<<<BDIM * CDIM, KKP, 0, stream>>>(A, kp, desc);
    dn_kernel<<<BDIM, KKP, 0, stream>>>(desc, dn);
    dist_kernel<<<dim3(4, 256, BDIM), 256, 0, stream>>>(desc, Bf, dn, minkey);
    finalize_kernel<<<BDIM, KKP, 0, stream>>>(minkey, kp, out);
}

// Round 2
// 153.215 us; speedup vs baseline: 2.2186x; 2.2186x over previous
//
#include <hip/hip_runtime.h>
#include <stdint.h>

#define BDIM 4
#define CDIM 512
#define HDIM 128
#define WDIM 128
#define HWDIM (HDIM*WDIM)
#define SADMP 16
#define BHW 8
#define KKP 256

using short8 = __attribute__((ext_vector_type(8))) short;
using f32x4  = __attribute__((ext_vector_type(4))) float;

__device__ __forceinline__ unsigned short f2bf(float f) {
    unsigned u = __float_as_uint(f);
    unsigned r = (u + 0x7fffu + ((u >> 16) & 1u)) >> 16;
    return (unsigned short)r;
}
__device__ __forceinline__ float bf2f(unsigned short h) {
    return __uint_as_float(((unsigned)h) << 16);
}
__device__ __forceinline__ unsigned int ordf(float f) {
    unsigned u = __float_as_uint(f);
    return (u & 0x80000000u) ? ~u : (u | 0x80000000u);
}

// ---------------- K1: resp[b][hw] = sum_c A[b][c][hw] ----------------
__global__ void resp_kernel(const float* __restrict__ A, float* __restrict__ resp) {
    int gid = blockIdx.x * blockDim.x + threadIdx.x;
    int b = gid / HWDIM, hw = gid % HWDIM;
    const float* p = A + (size_t)b * CDIM * HWDIM + hw;
    float s0 = 0.f, s1 = 0.f, s2 = 0.f, s3 = 0.f;
    #pragma unroll 4
    for (int c = 0; c < CDIM; c += 4) {
        s0 += p[(size_t)(c + 0) * HWDIM];
        s1 += p[(size_t)(c + 1) * HWDIM];
        s2 += p[(size_t)(c + 2) * HWDIM];
        s3 += p[(size_t)(c + 3) * HWDIM];
    }
    resp[gid] = (s0 + s1) + (s2 + s3);
}

// ---------------- K2: per-window argmax (first occurrence) ----------------
__global__ void argmax_kernel(const float* __restrict__ resp, int* __restrict__ kp) {
    int win = blockIdx.x;                 // b*K + k
    int b = win / KKP, k = win % KKP;
    int bi = k / SADMP, bj = k % SADMP;
    int l = threadIdx.x;                  // 0..63 == loc
    int r = l >> 3, c = l & 7;
    int h = bi * BHW + r, w = bj * BHW + c;
    float v = resp[b * HWDIM + h * WDIM + w];
    int idx = l;
    #pragma unroll
    for (int off = 32; off; off >>= 1) {
        float ov = __shfl_down(v, off);
        int   oi = __shfl_down(idx, off);
        if (ov > v || (ov == v && oi < idx)) { v = ov; idx = oi; }
    }
    if (l == 0) {
        int row = bi * BHW + (idx >> 3);
        int col = bj * BHW + (idx & 7);
        kp[win] = row * WDIM + col;
    }
}

// ---------------- K3: gather + hi/lo convert into MFMA-fragment order + dn ----------------
// fragbuf layout: uint4 at index (b*2+term)*16384 + mf*1024 + q*64 + lane
//   holds 8 bf16: A[m = mf*16 + (lane&15)][c = q*32 + (lane>>4)*8 + j]
__global__ void convert_kernel(const float* __restrict__ A, const int* __restrict__ kp,
                               uint4* __restrict__ frag, float* __restrict__ dn) {
    int blk = blockIdx.x;                 // b*16 + mf
    int b = blk >> 4, mf = blk & 15;
    int t = threadIdx.x;                  // 0..255
    int l = t & 63, q0 = t >> 6;
    int ml = l & 15;
    int m  = mf * 16 + ml;
    int cg = (l >> 4) * 8;
    int idx = kp[b * KKP + m];
    const float* Ab = A + (size_t)b * CDIM * HWDIM + idx;
    float sq = 0.f;
    #pragma unroll
    for (int qq = 0; qq < 4; qq++) {
        int q = q0 * 4 + qq;
        unsigned hi[4], lo[4];
        #pragma unroll
        for (int jj = 0; jj < 4; jj++) {
            int c0 = q * 32 + cg + jj * 2;
            float v0 = Ab[(size_t)c0 * HWDIM];
            float v1 = Ab[(size_t)(c0 + 1) * HWDIM];
            sq = fmaf(v0, v0, sq);
            sq = fmaf(v1, v1, sq);
            unsigned short h0 = f2bf(v0), h1 = f2bf(v1);
            unsigned short l0 = f2bf(v0 - bf2f(h0)), l1 = f2bf(v1 - bf2f(h1));
            hi[jj] = (unsigned)h0 | ((unsigned)h1 << 16);
            lo[jj] = (unsigned)l0 | ((unsigned)l1 << 16);
        }
        uint4 ph = make_uint4(hi[0], hi[1], hi[2], hi[3]);
        uint4 pl = make_uint4(lo[0], lo[1], lo[2], lo[3]);
        frag[((size_t)b * 2 + 0) * 16384 + mf * 1024 + q * 64 + l] = ph;
        frag[((size_t)b * 2 + 1) * 16384 + mf * 1024 + q * 64 + l] = pl;
    }
    // dn reduction: 16 partials per m (4 cg-groups x 4 q0-groups)
    __shared__ float red[16][17];
    red[ml][(l >> 4) * 4 + q0] = sq;
    __syncthreads();
    if (t < 16) {
        float s = 0.f;
        #pragma unroll
        for (int i = 0; i < 16; i++) s += red[t][i];
        dn[b * KKP + mf * 16 + t] = s;
    }
}

// ---------------- K4: MFMA dist + argmin ----------------
// grid (256 n-tiles, 4 batches), 512 threads.
// BM=256 (all keypoints), BN=64, BK=64 per step, bf16 hi/lo 3-term split.
__global__ __launch_bounds__(512) void dist_mfma_kernel(
    const uint4* __restrict__ fragA, const float* __restrict__ fb,
    const float* __restrict__ dn, unsigned long long* __restrict__ minkey)
{
    const int n0 = blockIdx.x * 64;
    const int b  = blockIdx.y;
    const int t  = threadIdx.x;
    const int l  = t & 63;
    const int w  = t >> 6;                // wave 0..7: rows w*32 .. w*32+31

    __shared__ uint4 sBq[2][704];         // [term][64 rows x 176B]
    __shared__ float bnp[8][64];
    __shared__ float bnf[64];
    __shared__ float dnl[256];

    char* sb0 = (char*)sBq[0];
    char* sb1 = (char*)sBq[1];

    if (t < 256) dnl[t] = dn[b * KKP + t];

    f32x4 acc[2][4] = {};                 // [mfl][nf]

    const int cbase = w * 8;              // staging c-offset within step
    const float* fbp = fb + (size_t)b * CDIM * HWDIM + n0 + l;
    float bnacc = 0.f;

    const int woff = (l * 176 + w * 16) ^ (((l >> 3) & 7) << 4);

    const short8* fA = (const short8*)fragA;
    const size_t baseHi = ((size_t)b * 2 + 0) * 16384;
    const size_t baseLo = ((size_t)b * 2 + 1) * 16384;

    float v[8];
    #pragma unroll
    for (int i = 0; i < 8; i++) v[i] = fbp[(size_t)(cbase + i) * HWDIM];

    for (int step = 0; step < 8; step++) {
        // convert + pack + LDS write (transposed [n][c] layout)
        unsigned hi[4], lo[4];
        #pragma unroll
        for (int jj = 0; jj < 4; jj++) {
            float v0 = v[jj * 2], v1 = v[jj * 2 + 1];
            bnacc = fmaf(v0, v0, bnacc);
            bnacc = fmaf(v1, v1, bnacc);
            unsigned short h0 = f2bf(v0), h1 = f2bf(v1);
            unsigned short l0 = f2bf(v0 - bf2f(h0)), l1 = f2bf(v1 - bf2f(h1));
            hi[jj] = (unsigned)h0 | ((unsigned)h1 << 16);
            lo[jj] = (unsigned)l0 | ((unsigned)l1 << 16);
        }
        *(uint4*)(sb0 + woff) = make_uint4(hi[0], hi[1], hi[2], hi[3]);
        *(uint4*)(sb1 + woff) = make_uint4(lo[0], lo[1], lo[2], lo[3]);
        __syncthreads();

        // prefetch next step's fb values (overlaps compute)
        if (step < 7) {
            #pragma unroll
            for (int i = 0; i < 8; i++)
                v[i] = fbp[(size_t)((step + 1) * 64 + cbase + i) * HWDIM];
        }

        #pragma unroll
        for (int ch = 0; ch < 2; ch++) {
            const int q = step * 2 + ch;
            short8 a_hi[2], a_lo[2];
            #pragma unroll
            for (int mfl = 0; mfl < 2; mfl++) {
                int mf = w * 2 + mfl;
                a_hi[mfl] = fA[baseHi + mf * 1024 + q * 64 + l];
                a_lo[mfl] = fA[baseLo + mf * 1024 + q * 64 + l];
            }
            #pragma unroll
            for (int nf = 0; nf < 4; nf++) {
                int n = nf * 16 + (l & 15);
                int boff = (n * 176 + ch * 64 + (l >> 4) * 16) ^ (((n >> 3) & 7) << 4);
                short8 b_hi = *(const short8*)(sb0 + boff);
                short8 b_lo = *(const short8*)(sb1 + boff);
                #pragma unroll
                for (int mfl = 0; mfl < 2; mfl++) {
                    acc[mfl][nf] = __builtin_amdgcn_mfma_f32_16x16x32_bf16(a_hi[mfl], b_hi, acc[mfl][nf], 0, 0, 0);
                    acc[mfl][nf] = __builtin_amdgcn_mfma_f32_16x16x32_bf16(a_hi[mfl], b_lo, acc[mfl][nf], 0, 0, 0);
                    acc[mfl][nf] = __builtin_amdgcn_mfma_f32_16x16x32_bf16(a_lo[mfl], b_hi, acc[mfl][nf], 0, 0, 0);
                }
            }
        }
        __syncthreads();
    }

    // bn reduction (8 c-group partials per column)
    bnp[w][l] = bnacc;
    __syncthreads();
    if (t < 64) {
        float s = 0.f;
        #pragma unroll
        for (int i = 0; i < 8; i++) s += bnp[i][t];
        bnf[t] = s;
    }
    __syncthreads();

    // epilogue: dist = dn - 2*cross + bn, packed argmin, atomicMin
    #pragma unroll
    for (int mfl = 0; mfl < 2; mfl++) {
        #pragma unroll
        for (int r = 0; r < 4; r++) {
            int m = w * 32 + mfl * 16 + (l >> 4) * 4 + r;
            float dnm = dnl[m];
            unsigned long long best = ~0ull;
            #pragma unroll
            for (int nf = 0; nf < 4; nf++) {
                int nloc = nf * 16 + (l & 15);
                float d = dnm - 2.f * acc[mfl][nf][r] + bnf[nloc];
                unsigned long long key = ((unsigned long long)ordf(d) << 32) | (unsigned)(n0 + nloc);
                if (key < best) best = key;
            }
            #pragma unroll
            for (int off = 1; off < 16; off <<= 1) {
                unsigned long long o = __shfl_xor(best, off);
                if (o < best) best = o;
            }
            if ((l & 15) == 0) atomicMin(&minkey[b * KKP + m], best);
        }
    }
}

// ---------------- K5: finalize ----------------
__global__ void finalize_kernel(const unsigned long long* __restrict__ minkey,
                                const int* __restrict__ kp,
                                float* __restrict__ out)
{
    int b = blockIdx.x;
    int k = threadIdx.x;
    unsigned long long key = minkey[b * KKP + k];
    unsigned n   = (unsigned)(key & 0xffffffffu);
    unsigned top = (unsigned)(key >> 32);
    unsigned fbits = (top & 0x80000000u) ? (top ^ 0x80000000u) : ~top;
    out[8 + b * KKP + k] = __uint_as_float(fbits);

    int idxA = kp[b * KKP + k];
    int rowA = idxA >> 7, colA = idxA & 127;
    int rowB = (int)(n >> 7), colB = (int)(n & 127);
    int drow = rowA - rowB, dcol = colA - colB;
    int code = (drow + 256) * 1024 + (dcol + 256);

    __shared__ int codes[KKP];
    __shared__ int keys[KKP];
    codes[k] = code;
    __syncthreads();
    int cnt = 0;
    for (int j = 0; j < KKP; j++) cnt += (codes[j] == code);
    keys[k] = cnt * 256 + (255 - k);
    __syncthreads();
    for (int s = 128; s; s >>= 1) {
        if (k < s) keys[k] = max(keys[k], keys[k + s]);
        __syncthreads();
    }
    if (k == 0) {
        int bestk = 255 - (keys[0] & 255);
        int bc = codes[bestk];
        int dr = bc / 1024 - 256, dc = bc % 1024 - 256;
        out[b * 2 + 0] = (float)dr;
        out[b * 2 + 1] = (float)dc;
    }
}

extern "C" void kernel_launch(void* const* d_in, const int* in_sizes, int n_in,
                              void* d_out, int out_size, void* d_ws, size_t ws_size,
                              hipStream_t stream) {
    const float* A  = (const float*)d_in[0];
    const float* Bf = (const float*)d_in[1];
    float* out = (float*)d_out;
    char* ws = (char*)d_ws;

    float* resp = (float*)ws;                                   // 256 KB
    int*   kp   = (int*)(ws + 262144);                          // 4 KB
    float* dn   = (float*)(ws + 266240);                        // 4 KB
    unsigned long long* minkey = (unsigned long long*)(ws + 270336); // 8 KB
    uint4* frag = (uint4*)(ws + 278528);                        // 2 MB

    hipMemsetAsync(minkey, 0xFF, BDIM * KKP * sizeof(unsigned long long), stream);
    resp_kernel<<<BDIM * HWDIM / 256, 256, 0, stream>>>(A, resp);
    argmax_kernel<<<BDIM * KKP, 64, 0, stream>>>(resp, kp);
    convert_kernel<<<BDIM * 16, 256, 0, stream>>>(A, kp, frag, dn);
    dist_mfma_kernel<<<dim3(256, BDIM), 512, 0, stream>>>(frag, Bf, dn, minkey);
    finalize_kernel<<<BDIM, KKP, 0, stream>>>(minkey, kp, out);
}